// Round 3
// baseline (407.209 us; speedup 1.0000x reference)
//
#include <hip/hip_runtime.h>

typedef unsigned int   u32;
typedef unsigned short u16;

typedef _Float16 h2  __attribute__((ext_vector_type(2)));
typedef _Float16 h8  __attribute__((ext_vector_type(8)));
typedef float    f32x4 __attribute__((ext_vector_type(4)));

#define M_TOK 128

__device__ __forceinline__ void lds_barrier() {
    // CK block_sync_lds: drain LDS only; global loads stay in flight across barrier
    asm volatile("s_waitcnt lgkmcnt(0)\n\ts_barrier" ::: "memory");
}
__device__ __forceinline__ u16 f2h_(float f) {
    _Float16 h = (_Float16)f; return __builtin_bit_cast(u16, h);
}
__device__ __forceinline__ float h2f_(u16 b) {
    _Float16 h = __builtin_bit_cast(_Float16, b); return (float)h;
}

// ---------------------------------------------------------------------------
// RMSNorm: one block per token row (4096 cols), fp32 in -> fp16 out
// ---------------------------------------------------------------------------
__launch_bounds__(256)
__global__ void rmsnorm_k(const float* __restrict__ in, const float* __restrict__ w,
                          u16* __restrict__ out) {
    const int row = blockIdx.x;
    const float* x = in + (size_t)row * 4096;
    float ss = 0.f;
#pragma unroll
    for (int j = 0; j < 16; ++j) {
        float v = x[threadIdx.x + 256 * j];
        ss += v * v;
    }
#pragma unroll
    for (int off = 32; off > 0; off >>= 1) ss += __shfl_down(ss, off, 64);
    __shared__ float ws4[4];
    if ((threadIdx.x & 63) == 0) ws4[threadIdx.x >> 6] = ss;
    __syncthreads();
    float total = ws4[0] + ws4[1] + ws4[2] + ws4[3];
    float r = rsqrtf(total * (1.f / 4096.f) + 1e-6f);
    u16* o = out + (size_t)row * 4096;
#pragma unroll
    for (int j = 0; j < 16; ++j) {
        int i = threadIdx.x + 256 * j;
        o[i] = f2h_(x[i] * r * w[i]);
    }
}

// ---------------------------------------------------------------------------
// AWQ GEMM (fp16 path): A (fp16, 128 x K row-major) @ dequant(W) (K x N).
// BM=128, BN=64, BK=64. B-only LDS, double-buffered, 1 barrier per step.
// A-frags global->VGPR (depth-1 prefetch); qw depth-2; z/sc per-group depth-2.
// Dequant: v_perm + v_and_or (fp16 magic 1024+n) + v_pk_add + v_pk_mul.
// ---------------------------------------------------------------------------
__launch_bounds__(256, 3)
__global__ void gemm_awq(const u16* __restrict__ A, const int* __restrict__ qw,
                         const int* __restrict__ qz, const float* __restrict__ sc,
                         u16* __restrict__ part,
                         int Astride, int qws, int scs, int N, int K, int kchunk) {
    // 2 buffers x 64 rows x 144 B (64 fp16 + 16 pad). Row stride 36 words
    // == 4 mod 32 -> 2-way max on b128 reads; dequant b32 writes conflict-free.
    __shared__ __align__(16) char ldsB[2 * 9216];

    const int tid = threadIdx.x;
    // pair-swizzle: tiles 2u,2u+1 -> same XCD (assumes round-robin bid%8)
    int tile;
    {
        const int T = gridDim.x, bx = blockIdx.x, base = (T >> 4) << 4;
        if (bx < base) { int a = bx >> 4, r = bx & 15; tile = a * 16 + ((r & 7) << 1) + (r >> 3); }
        else tile = bx;
    }
    const int n0 = tile * 64;
    const int sk = blockIdx.y;
    const int kc0 = sk * kchunk;
    const int kend = min(kc0 + kchunk, K);
    const int nsteps = (kend - kc0) >> 6;   // even, >= 8 for all our launches

    const int w = tid >> 6, lane = tid & 63;
    const int wr = (w >> 1) * 64, wc = (w & 1) * 32;
    const int q = lane >> 4, l16 = lane & 15;

    // dequant role: 256 threads = 32 k-pairs x 8 packed-cols
    const int kp = tid & 31;
    const int p = tid >> 5;
    const int pc = (n0 >> 3) + p;

    // A fragment base pointers (row-major fp16)
    const u16* ab[4];
#pragma unroll
    for (int mt = 0; mt < 4; ++mt)
        ab[mt] = A + (size_t)(wr + mt * 16 + l16) * Astride + q * 8;

    f32x4 acc[4][2] = {};
    h2 mz[8], s2[8];
    float rs[8];
    u32 rawz = 0;
    const int SH[8] = {0, 16, 4, 20, 8, 24, 12, 28};

    auto ldqw = [&](int k, u32& a, u32& b) {
        a = (u32)qw[(size_t)(k + 2 * kp) * qws + pc];
        b = (u32)qw[(size_t)(k + 2 * kp + 1) * qws + pc];
    };
    auto lda = [&](int k, uint4(&dst)[8]) {
#pragma unroll
        for (int mt = 0; mt < 4; ++mt) {
            dst[mt * 2 + 0] = *(const uint4*)(ab[mt] + k);
            dst[mt * 2 + 1] = *(const uint4*)(ab[mt] + k + 32);
        }
    };
    auto gconv = [&](u32 zword, const float* s8) {
#pragma unroll
        for (int j = 0; j < 8; ++j) {
            u32 zj = (zword >> SH[j]) & 15u;
            mz[j] = __builtin_bit_cast(h2, 0xE400E400u | zj | (zj << 16));
            _Float16 hs = (_Float16)s8[j];
            s2[j] = (h2){hs, hs};
        }
    };
    auto deq = [&](u32 w0, u32 w1, char* wb) {
        char* bb = wb + p * 1152 + kp * 4;    // p*8 rows * 144 B
        u32 w0s = w0 >> 4, w1s = w1 >> 4;
        auto emit = [&](int j, u32 a0, u32 a1, int b) {
            u32 t = __builtin_amdgcn_perm(a1, a0, (u32)(b | ((b + 4) << 16)));
            u32 u = (t & 0x000F000Fu) | 0x64006400u;      // fp16 (1024+n) pair
            h2 v = (__builtin_bit_cast(h2, u) + mz[j]) * s2[j];
            *(u32*)(bb + j * 144) = __builtin_bit_cast(u32, v);
        };
        emit(0, w0, w1, 0);  emit(4, w0, w1, 1);
        emit(1, w0, w1, 2);  emit(5, w0, w1, 3);
        emit(2, w0s, w1s, 0); emit(6, w0s, w1s, 1);
        emit(3, w0s, w1s, 2); emit(7, w0s, w1s, 3);
    };
    auto mm = [&](const uint4(&ac)[8], const char* rb) {
        uint4 bf[4];
#pragma unroll
        for (int nt = 0; nt < 2; ++nt)
#pragma unroll
            for (int h = 0; h < 2; ++h)
                bf[nt * 2 + h] = *(const uint4*)(rb + (wc + nt * 16 + l16) * 144 + h * 64 + q * 16);
#pragma unroll
        for (int mt = 0; mt < 4; ++mt)
#pragma unroll
            for (int nt = 0; nt < 2; ++nt)
#pragma unroll
                for (int h = 0; h < 2; ++h)
                    acc[mt][nt] = __builtin_amdgcn_mfma_f32_16x16x32_f16(
                        __builtin_bit_cast(h8, ac[mt * 2 + h]),
                        __builtin_bit_cast(h8, bf[nt * 2 + h]),
                        acc[mt][nt], 0, 0, 0);
    };

    // ---- prologue ----
    const int g0 = kc0 >> 7;
    u32 q0a, q0b, q1a, q1b, q2a, q2b;
    uint4 aA[8], aB[8];
    ldqw(kc0, q0a, q0b);            // tile 0 (consumed below)
    lda(kc0, aA);                   // tile 0 A-frags
    ldqw(kc0 + 64, q1a, q1b);       // tile 1
    ldqw(kc0 + 128, q2a, q2b);      // tile 2
    {
        u32 z0 = (u32)qz[(size_t)g0 * qws + pc];
        const float* sp = sc + (size_t)g0 * scs + n0 + p * 8;
        float t0[8];
        *(float4*)&t0[0] = *(const float4*)sp;
        *(float4*)&t0[4] = *(const float4*)(sp + 4);
        gconv(z0, t0);
    }
    rawz = (u32)qz[(size_t)(g0 + 1) * qws + pc];
    {
        const float* sp = sc + (size_t)(g0 + 1) * scs + n0 + p * 8;
        *(float4*)&rs[0] = *(const float4*)sp;
        *(float4*)&rs[4] = *(const float4*)(sp + 4);
    }
    deq(q0a, q0b, ldsB);            // tile 0 -> buf0
    lds_barrier();

    // ---- main loop: step s MFMAs tile s, dequants tile s+1, prefetches ----
    auto body = [&](int s, uint4(&ac)[8], uint4(&an)[8], char* rb, char* wb, bool conv) {
        const int kA = kc0 + ((s + 1) << 6);
        const int kQ = kc0 + ((s + 3) << 6);
        if (kA < kend) lda(kA, an);
        u32 nqa = 0, nqb = 0;
        if (kQ < kend) ldqw(kQ, nqa, nqb);
        if (conv && kA < kend) {
            float t0[8];
#pragma unroll
            for (int j = 0; j < 8; ++j) t0[j] = rs[j];
            gconv(rawz, t0);
            const int gn = (kA >> 7) + 1;
            if ((gn << 7) < kend) {
                rawz = (u32)qz[(size_t)gn * qws + pc];
                const float* sp = sc + (size_t)gn * scs + n0 + p * 8;
                *(float4*)&rs[0] = *(const float4*)sp;
                *(float4*)&rs[4] = *(const float4*)(sp + 4);
            }
        }
        if (s + 1 < nsteps) deq(q1a, q1b, wb);
        mm(ac, rb);
        lds_barrier();
        q1a = q2a; q1b = q2b; q2a = nqa; q2b = nqb;
    };
    for (int s = 0; s < nsteps; s += 2) {
        body(s,     aA, aB, ldsB,        ldsB + 9216, false);
        body(s + 1, aB, aA, ldsB + 9216, ldsB,        true);
    }

    // ---- epilogue: fp16 partial store ----
    u16* pp = part + (size_t)sk * M_TOK * N;
#pragma unroll
    for (int mt = 0; mt < 4; ++mt)
#pragma unroll
        for (int nt = 0; nt < 2; ++nt) {
            const int n = n0 + wc + nt * 16 + l16;
#pragma unroll
            for (int r = 0; r < 4; ++r) {
                const int m = wr + mt * 16 + q * 4 + r;
                pp[(size_t)m * N + n] = f2h_(acc[mt][nt][r]);
            }
        }
}

// ---------------------------------------------------------------------------
// Reduce split-K fp16 partials -> fp16
// ---------------------------------------------------------------------------
__launch_bounds__(256)
__global__ void reduce_f16(const u16* __restrict__ part, u16* __restrict__ out,
                           int total, int SK) {
    const int i = blockIdx.x * 256 + threadIdx.x;
    float s = 0.f;
    for (int k = 0; k < SK; ++k) s += h2f_(part[(size_t)k * total + i]);
    out[i] = f2h_(s);
}

// Reduce split-K fp16 partials + fp32 residual -> fp32
__launch_bounds__(256)
__global__ void reduce_add_f32(const u16* __restrict__ part, const float* __restrict__ resin,
                               float* __restrict__ out, int total, int SK) {
    const int i = blockIdx.x * 256 + threadIdx.x;
    float s = resin[i];
    for (int k = 0; k < SK; ++k) s += h2f_(part[(size_t)k * total + i]);
    out[i] = s;
}

// ---------------------------------------------------------------------------
// SiLU(gate) * up from gate_up fp16 partials [3][128][22016] -> act fp16
// ---------------------------------------------------------------------------
__launch_bounds__(256)
__global__ void silu_mul(const u16* __restrict__ part, u16* __restrict__ act) {
    const int n = blockIdx.x * 256 + threadIdx.x;   // 0..11007
    const int m = blockIdx.y;
    const size_t plane = (size_t)M_TOK * 22016;
    const size_t base = (size_t)m * 22016;
    float g = 0.f, u = 0.f;
#pragma unroll
    for (int k = 0; k < 3; ++k) {
        g += h2f_(part[(size_t)k * plane + base + n]);
        u += h2f_(part[(size_t)k * plane + base + n + 11008]);
    }
    float a = g / (1.f + __expf(-g)) * u;
    act[(size_t)m * 11008 + n] = f2h_(a);
}

// ---------------------------------------------------------------------------
extern "C" void kernel_launch(void* const* d_in, const int* in_sizes, int n_in,
                              void* d_out, int out_size, void* d_ws, size_t ws_size,
                              hipStream_t stream) {
    const float* x      = (const float*)d_in[0];
    const float* ln1_w  = (const float*)d_in[1];
    const float* ln2_w  = (const float*)d_in[2];
    const int*   qkv_qw = (const int*)d_in[3];
    const int*   qkv_qz = (const int*)d_in[4];
    const float* qkv_sc = (const float*)d_in[5];
    const int*   o_qw   = (const int*)d_in[6];
    const int*   o_qz   = (const int*)d_in[7];
    const float* o_sc   = (const float*)d_in[8];
    const int*   gu_qw  = (const int*)d_in[9];
    const int*   gu_qz  = (const int*)d_in[10];
    const float* gu_sc  = (const float*)d_in[11];
    const int*   dn_qw  = (const int*)d_in[12];
    const int*   dn_qz  = (const int*)d_in[13];
    const float* dn_sc  = (const float*)d_in[14];
    float* out = (float*)d_out;

    // ws layout (~21.8 MB)
    char* ws = (char*)d_ws;
    u16*   pbuf = (u16*)(ws);                       // partials: max 16.9 MB (gu SK=3)
    u16*   act  = (u16*)(ws + 16908288);            // 2.75 MB fp16
    float* res2 = (float*)(ws + 19726336);          // 2 MB fp32
    u16*   slot = (u16*)(ws + 21823488);            // 1 MB fp16 (h1/qb/h2)

    const int TOT = M_TOK * 4096;                   // 524288

    // h1 = rmsnorm(x, ln1)
    rmsnorm_k<<<128, 256, 0, stream>>>(x, ln1_w, slot);

    // q = h1 @ Wqkv[:, :4096]   (K=4096, 64 tiles, SK=8, kchunk=512)
    gemm_awq<<<dim3(64, 8), 256, 0, stream>>>(slot, qkv_qw, qkv_qz, qkv_sc, pbuf,
                                              4096, 1536, 12288, 4096, 4096, 512);
    reduce_f16<<<2048, 256, 0, stream>>>(pbuf, slot, TOT, 8);

    // attn = q @ Wo ; res2 = x + attn
    gemm_awq<<<dim3(64, 8), 256, 0, stream>>>(slot, o_qw, o_qz, o_sc, pbuf,
                                              4096, 512, 4096, 4096, 4096, 512);
    reduce_add_f32<<<2048, 256, 0, stream>>>(pbuf, x, res2, TOT, 8);

    // h2 = rmsnorm(res2, ln2)
    rmsnorm_k<<<128, 256, 0, stream>>>(res2, ln2_w, slot);

    // gate_up = h2 @ Wgu  (344 tiles, SK=3, kchunk=1408)
    gemm_awq<<<dim3(344, 3), 256, 0, stream>>>(slot, gu_qw, gu_qz, gu_sc, pbuf,
                                               4096, 2752, 22016, 22016, 4096, 1408);
    silu_mul<<<dim3(43, 128), 256, 0, stream>>>(pbuf, act);

    // down = act @ Wdn  (K=11008, SK=8, kchunk=1408); out = res2 + down
    gemm_awq<<<dim3(64, 8), 256, 0, stream>>>(act, dn_qw, dn_qz, dn_sc, pbuf,
                                              11008, 512, 4096, 4096, 11008, 1408);
    reduce_add_f32<<<2048, 256, 0, stream>>>(pbuf, res2, out, TOT, 8);
}

// Round 4
// 336.219 us; speedup vs baseline: 1.2111x; 1.2111x over previous
//
#include <hip/hip_runtime.h>

typedef unsigned int   u32;
typedef unsigned short u16;

typedef _Float16 h2  __attribute__((ext_vector_type(2)));
typedef _Float16 h8  __attribute__((ext_vector_type(8)));
typedef float    f32x4 __attribute__((ext_vector_type(4)));

#define M_TOK 128

__device__ __forceinline__ u16 f2h_(float f) {
    _Float16 h = (_Float16)f; return __builtin_bit_cast(u16, h);
}
__device__ __forceinline__ float h2f_(u16 b) {
    _Float16 h = __builtin_bit_cast(_Float16, b); return (float)h;
}
// accumulate 8 fp16 (packed in uint4) into float[8]
__device__ __forceinline__ void acc8(uint4 v, float* s) {
#pragma unroll
    for (int i = 0; i < 4; ++i) {
        u32 w = ((const u32*)&v)[i];
        s[2 * i]     += h2f_((u16)(w & 0xFFFF));
        s[2 * i + 1] += h2f_((u16)(w >> 16));
    }
}

// A-fragment-major layout: elem offset for logical (m, k):
//   kb=k/32, q=(k/8)&3, j=k&7, mt=m/16, l16=m&15
//   off = ((kb*8+mt)*64 + q*16 + l16)*8 + j    (fp16 elements)
// A wave reading frag (kb,mt) does ONE coalesced 16B/lane load.

// ---------------------------------------------------------------------------
// RMSNorm: one block per token row, fp32 in -> fp16 out in Afrag layout
// ---------------------------------------------------------------------------
__launch_bounds__(256)
__global__ void rmsnorm_k(const float* __restrict__ in, const float* __restrict__ w,
                          u16* __restrict__ out) {
    const int row = blockIdx.x;
    const float* x = in + (size_t)row * 4096;
    float ss = 0.f;
#pragma unroll
    for (int j = 0; j < 16; ++j) {
        float v = x[threadIdx.x + 256 * j];
        ss += v * v;
    }
#pragma unroll
    for (int off = 32; off > 0; off >>= 1) ss += __shfl_down(ss, off, 64);
    __shared__ float ws4[4];
    if ((threadIdx.x & 63) == 0) ws4[threadIdx.x >> 6] = ss;
    __syncthreads();
    float total = ws4[0] + ws4[1] + ws4[2] + ws4[3];
    float r = rsqrtf(total * (1.f / 4096.f) + 1e-6f);
    const int mt = row >> 4, l16 = row & 15;
#pragma unroll
    for (int c2 = 0; c2 < 2; ++c2) {
        int c = threadIdx.x * 2 + c2;        // 8-elem chunk index 0..511
        int kb = c >> 2, qq = c & 3;
        u16 o8[8];
#pragma unroll
        for (int j = 0; j < 8; ++j) {
            int i = c * 8 + j;
            o8[j] = f2h_(x[i] * r * w[i]);
        }
        *(uint4*)(out + ((size_t)(kb * 8 + mt) * 64 + qq * 16 + l16) * 8) = *(const uint4*)o8;
    }
}

// ---------------------------------------------------------------------------
// AWQ GEMM, barrier-free. A in Afrag layout. Per wave: 128m x 32n strip.
// BK=64 per iter. Private per-wave LDS B buffer (in-order LDS => no barrier).
// Split-K partials (fp16, row-major [sk][128][N]).
// ---------------------------------------------------------------------------
__launch_bounds__(256, 2)
__global__ void gemm_awq(const u16* __restrict__ A, const int* __restrict__ qw,
                         const int* __restrict__ qz, const float* __restrict__ sc,
                         u16* __restrict__ part,
                         int qws, int scs, int N, int K, int kchunk) {
    // per-wave region: 32 rows x 144 B (64 fp16 + 16B pad). stride 36 words
    // == 4 mod 32 -> worst 2-way on b128 reads (free); b32 writes conflict-free.
    __shared__ __align__(16) char ldsB[4 * 4608];

    const int tid = threadIdx.x, w = tid >> 6, lane = tid & 63;
    const int q = lane >> 4, l16 = lane & 15;
    const int n0w = blockIdx.x * 128 + w * 32;
    const int pc0 = n0w >> 3;
    const int kp = lane & 31, h = lane >> 5;
    const int sk = blockIdx.y, kc0 = sk * kchunk, kend = min(kc0 + kchunk, K);

    char* myB   = ldsB + w * 4608;
    char* wbase = myB + kp * 4;
    const u16* Ala = A + lane * 8;
    const int pA = pc0 + h, pB = pc0 + h + 2;

    f32x4 acc[8][2] = {};
    h2 mzv[8], s2v[8];
    const int SH[8] = {0, 16, 4, 20, 8, 24, 12, 28};

    auto ldqw = [&](int k, u32* d) {
        d[0] = (u32)qw[(size_t)(k + 2 * kp) * qws + pA];
        d[1] = (u32)qw[(size_t)(k + 2 * kp + 1) * qws + pA];
        d[2] = (u32)qw[(size_t)(k + 2 * kp) * qws + pB];
        d[3] = (u32)qw[(size_t)(k + 2 * kp + 1) * qws + pB];
    };
    auto conv = [&](u32 z, const float* s8) {
#pragma unroll
        for (int j = 0; j < 8; ++j) {
            u32 zj = (z >> SH[j]) & 15u;
            mzv[j] = __builtin_bit_cast(h2, 0xE400E400u | zj | (zj << 16));
            _Float16 hs = (_Float16)s8[j];
            s2v[j] = (h2){hs, hs};
        }
    };
    auto emit8 = [&](u32 w0, u32 w1, int nb) {
        char* bb = wbase + nb * 144;
        u32 w0s = w0 >> 4, w1s = w1 >> 4;
        auto em = [&](int j, u32 a0, u32 a1, int b) {
            u32 t = __builtin_amdgcn_perm(a1, a0, (u32)(b | ((b + 4) << 16)));
            u32 u = (t & 0x000F000Fu) | 0x64006400u;     // fp16 (1024+n) pair
            h2 v = (__builtin_bit_cast(h2, u) + mzv[j]) * s2v[j];
            *(u32*)(bb + j * 144) = __builtin_bit_cast(u32, v);
        };
        em(0, w0, w1, 0);  em(4, w0, w1, 1);  em(1, w0, w1, 2);  em(5, w0, w1, 3);
        em(2, w0s, w1s, 0); em(6, w0s, w1s, 1); em(3, w0s, w1s, 2); em(7, w0s, w1s, 3);
    };

    u32 qc[4], qn[4] = {0, 0, 0, 0};
    // ---- prologue: dequant step 0, prefetch step 1 ----
    ldqw(kc0, qc);
    {
        int g = kc0 >> 7;
        u32 z0 = (u32)qz[(size_t)g * qws + pA], z1 = (u32)qz[(size_t)g * qws + pB];
        const float* sb = sc + (size_t)g * scs + n0w + h * 8;
        float s8a[8], s8b[8];
        *(float4*)&s8a[0] = *(const float4*)sb;        *(float4*)&s8a[4] = *(const float4*)(sb + 4);
        *(float4*)&s8b[0] = *(const float4*)(sb + 16); *(float4*)&s8b[4] = *(const float4*)(sb + 20);
        conv(z0, s8a); emit8(qc[0], qc[1], h * 8);
        conv(z1, s8b); emit8(qc[2], qc[3], 16 + h * 8);
    }
    if (kc0 + 64 < kend) ldqw(kc0 + 64, qn);

    // ---- barrier-free main loop ----
    for (int k0 = kc0; k0 < kend; k0 += 64) {
        const bool kn1 = (k0 + 64) < kend, kn2 = (k0 + 128) < kend;
        // z/sc loads for step s+1 (issued early; consumed after B-reads/qw-pf)
        u32 z0 = 0, z1 = 0; float s8a[8], s8b[8];
        if (kn1) {
            int g = (k0 + 64) >> 7;
            z0 = (u32)qz[(size_t)g * qws + pA]; z1 = (u32)qz[(size_t)g * qws + pB];
            const float* sb = sc + (size_t)g * scs + n0w + h * 8;
            *(float4*)&s8a[0] = *(const float4*)sb;        *(float4*)&s8a[4] = *(const float4*)(sb + 4);
            *(float4*)&s8b[0] = *(const float4*)(sb + 16); *(float4*)&s8b[4] = *(const float4*)(sb + 20);
        }
        // A-frag loads (coalesced), consumed by MFMA at iter end
        uint4 af[2][8];
        const int kb0 = k0 >> 5;
#pragma unroll
        for (int c = 0; c < 2; ++c)
#pragma unroll
            for (int mt = 0; mt < 8; ++mt)
                af[c][mt] = *(const uint4*)(Ala + (size_t)((kb0 + c) * 8 + mt) * 512);
        // B-frag reads for step s (writes from prev iter long drained)
        uint4 bv[2][2];
#pragma unroll
        for (int c = 0; c < 2; ++c)
#pragma unroll
            for (int nt = 0; nt < 2; ++nt)
                bv[c][nt] = *(const uint4*)(myB + (nt * 16 + l16) * 144 + c * 64 + q * 16);
        u32 qf[4] = {0, 0, 0, 0};
        if (kn2) ldqw(k0 + 128, qf);
        // dequant step s+1 into same private region (in-order LDS after reads)
        if (kn1) {
            conv(z0, s8a); emit8(qn[0], qn[1], h * 8);
            conv(z1, s8b); emit8(qn[2], qn[3], 16 + h * 8);
        }
        // MFMA step s
#pragma unroll
        for (int c = 0; c < 2; ++c)
#pragma unroll
            for (int mt = 0; mt < 8; ++mt)
#pragma unroll
                for (int nt = 0; nt < 2; ++nt)
                    acc[mt][nt] = __builtin_amdgcn_mfma_f32_16x16x32_f16(
                        __builtin_bit_cast(h8, af[c][mt]),
                        __builtin_bit_cast(h8, bv[c][nt]),
                        acc[mt][nt], 0, 0, 0);
#pragma unroll
        for (int i = 0; i < 4; ++i) qn[i] = qf[i];
    }

    // ---- epilogue: fp16 partial store (row-major plane) ----
    u16* pp = part + (size_t)sk * M_TOK * N;
#pragma unroll
    for (int mt = 0; mt < 8; ++mt)
#pragma unroll
        for (int nt = 0; nt < 2; ++nt) {
            const int n = n0w + nt * 16 + l16;
#pragma unroll
            for (int r = 0; r < 4; ++r) {
                const int m = mt * 16 + q * 4 + r;
                pp[(size_t)m * N + n] = f2h_(acc[mt][nt][r]);
            }
        }
}

// ---------------------------------------------------------------------------
// Reduce SK fp16 partial planes [sk][128][4096] -> fp16 in Afrag layout
// ---------------------------------------------------------------------------
__launch_bounds__(256)
__global__ void reduce_to_afrag(const u16* __restrict__ part, u16* __restrict__ out,
                                int SK) {
    const int idx = blockIdx.x * 256 + threadIdx.x;   // 0..65535
    const int m = idx >> 9, c = idx & 511;
    float s[8] = {};
    for (int k = 0; k < SK; ++k)
        acc8(*(const uint4*)(part + (size_t)k * 524288 + (size_t)m * 4096 + c * 8), s);
    const int kb = c >> 2, qq = c & 3, mt = m >> 4, l16 = m & 15;
    u16 o8[8];
#pragma unroll
    for (int j = 0; j < 8; ++j) o8[j] = f2h_(s[j]);
    *(uint4*)(out + ((size_t)(kb * 8 + mt) * 64 + qq * 16 + l16) * 8) = *(const uint4*)o8;
}

// Reduce SK fp16 partial planes + fp32 residual -> fp32 (row-major)
__launch_bounds__(256)
__global__ void reduce_add_f32(const u16* __restrict__ part, const float* __restrict__ resin,
                               float* __restrict__ out, int SK) {
    const int idx = blockIdx.x * 256 + threadIdx.x;
    const size_t base = (size_t)idx * 8;
    float s[8];
    *(float4*)&s[0] = *(const float4*)(resin + base);
    *(float4*)&s[4] = *(const float4*)(resin + base + 4);
    for (int k = 0; k < SK; ++k)
        acc8(*(const uint4*)(part + (size_t)k * 524288 + base), s);
    *(float4*)(out + base)     = *(const float4*)&s[0];
    *(float4*)(out + base + 4) = *(const float4*)&s[4];
}

// ---------------------------------------------------------------------------
// SiLU(gate)*up from gu partials [3][128][22016] -> act fp16 in Afrag layout
// ---------------------------------------------------------------------------
__launch_bounds__(256)
__global__ void silu_mul(const u16* __restrict__ part, u16* __restrict__ act) {
    const int idx = blockIdx.x * 256 + threadIdx.x;   // 0..176127
    const int m = idx / 1376, c = idx - m * 1376;
    const int nb = c * 8;
    float g[8] = {}, u[8] = {};
    for (int k = 0; k < 3; ++k) {
        const size_t base = (size_t)k * 2818048 + (size_t)m * 22016 + nb;
        acc8(*(const uint4*)(part + base), g);
        acc8(*(const uint4*)(part + base + 11008), u);
    }
    const int kb = nb >> 5, qq = (nb >> 3) & 3, mt = m >> 4, l16 = m & 15;
    u16 o8[8];
#pragma unroll
    for (int j = 0; j < 8; ++j) {
        float a = g[j] / (1.f + __expf(-g[j])) * u[j];
        o8[j] = f2h_(a);
    }
    *(uint4*)(act + ((size_t)(kb * 8 + mt) * 64 + qq * 16 + l16) * 8) = *(const uint4*)o8;
}

// ---------------------------------------------------------------------------
extern "C" void kernel_launch(void* const* d_in, const int* in_sizes, int n_in,
                              void* d_out, int out_size, void* d_ws, size_t ws_size,
                              hipStream_t stream) {
    const float* x      = (const float*)d_in[0];
    const float* ln1_w  = (const float*)d_in[1];
    const float* ln2_w  = (const float*)d_in[2];
    const int*   qkv_qw = (const int*)d_in[3];
    const int*   qkv_qz = (const int*)d_in[4];
    const float* qkv_sc = (const float*)d_in[5];
    const int*   o_qw   = (const int*)d_in[6];
    const int*   o_qz   = (const int*)d_in[7];
    const float* o_sc   = (const float*)d_in[8];
    const int*   gu_qw  = (const int*)d_in[9];
    const int*   gu_qz  = (const int*)d_in[10];
    const float* gu_sc  = (const float*)d_in[11];
    const int*   dn_qw  = (const int*)d_in[12];
    const int*   dn_qz  = (const int*)d_in[13];
    const float* dn_sc  = (const float*)d_in[14];
    float* out = (float*)d_out;

    // ws layout (~22.9 MB, same footprint as R3 which passed)
    char* ws = (char*)d_ws;
    u16*   pbuf = (u16*)(ws);                 // partials: max 16.9 MB (gu SK=3)
    u16*   act  = (u16*)(ws + 16908288);      // 2.75 MB fp16 (Afrag)
    float* res2 = (float*)(ws + 19726336);    // 2 MB fp32
    u16*   slot = (u16*)(ws + 21823488);      // 1 MB fp16 Afrag (h1/qb/h2)

    // h1 = rmsnorm(x, ln1)  -> Afrag
    rmsnorm_k<<<128, 256, 0, stream>>>(x, ln1_w, slot);

    // q = h1 @ Wqkv[:, :4096]   (32 tiles x SK16, kchunk=256)
    gemm_awq<<<dim3(32, 16), 256, 0, stream>>>(slot, qkv_qw, qkv_qz, qkv_sc, pbuf,
                                               1536, 12288, 4096, 4096, 256);
    reduce_to_afrag<<<256, 256, 0, stream>>>(pbuf, slot, 16);

    // attn = q @ Wo ; res2 = x + attn
    gemm_awq<<<dim3(32, 16), 256, 0, stream>>>(slot, o_qw, o_qz, o_sc, pbuf,
                                               512, 4096, 4096, 4096, 256);
    reduce_add_f32<<<256, 256, 0, stream>>>(pbuf, x, res2, 16);

    // h2 = rmsnorm(res2, ln2) -> Afrag
    rmsnorm_k<<<128, 256, 0, stream>>>(res2, ln2_w, slot);

    // gate_up = h2 @ Wgu   (172 tiles x SK3, kchunk=1408)
    gemm_awq<<<dim3(172, 3), 256, 0, stream>>>(slot, gu_qw, gu_qz, gu_sc, pbuf,
                                               2752, 22016, 22016, 4096, 1408);
    silu_mul<<<688, 256, 0, stream>>>(pbuf, act);

    // down = act @ Wdn   (32 tiles x SK16, kchunk=704); out = res2 + down
    gemm_awq<<<dim3(32, 16), 256, 0, stream>>>(act, dn_qw, dn_qz, dn_sc, pbuf,
                                               512, 4096, 4096, 11008, 704);
    reduce_add_f32<<<256, 256, 0, stream>>>(pbuf, res2, out, 16);
}

// Round 5
// 317.916 us; speedup vs baseline: 1.2809x; 1.0576x over previous
//
#include <hip/hip_runtime.h>

typedef unsigned int   u32;
typedef unsigned short u16;

typedef _Float16 h2  __attribute__((ext_vector_type(2)));
typedef _Float16 h8  __attribute__((ext_vector_type(8)));
typedef float    f32x4 __attribute__((ext_vector_type(4)));

#define M_TOK 128

__device__ __forceinline__ u16 f2h_(float f) {
    _Float16 h = (_Float16)f; return __builtin_bit_cast(u16, h);
}
__device__ __forceinline__ float h2f_(u16 b) {
    _Float16 h = __builtin_bit_cast(_Float16, b); return (float)h;
}
// accumulate 8 fp16 (packed in uint4) into float[8]
__device__ __forceinline__ void acc8(uint4 v, float* s) {
#pragma unroll
    for (int i = 0; i < 4; ++i) {
        u32 w = ((const u32*)&v)[i];
        s[2 * i]     += h2f_((u16)(w & 0xFFFF));
        s[2 * i + 1] += h2f_((u16)(w >> 16));
    }
}

// A-fragment-major layout: elem offset for logical (m, k):
//   kb=k/32, q=(k/8)&3, j=k&7, mt=m/16, l16=m&15
//   off = ((kb*8+mt)*64 + q*16 + l16)*8 + j    (fp16 elements)
// A wave reading frag (kb,mt) does ONE coalesced 16B/lane load.

// ---------------------------------------------------------------------------
// RMSNorm: one block per token row, fp32 in -> fp16 out in Afrag layout
// ---------------------------------------------------------------------------
__launch_bounds__(256)
__global__ void rmsnorm_k(const float* __restrict__ in, const float* __restrict__ w,
                          u16* __restrict__ out) {
    const int row = blockIdx.x;
    const float* x = in + (size_t)row * 4096;
    float ss = 0.f;
#pragma unroll
    for (int j = 0; j < 16; ++j) {
        float v = x[threadIdx.x + 256 * j];
        ss += v * v;
    }
#pragma unroll
    for (int off = 32; off > 0; off >>= 1) ss += __shfl_down(ss, off, 64);
    __shared__ float ws4[4];
    if ((threadIdx.x & 63) == 0) ws4[threadIdx.x >> 6] = ss;
    __syncthreads();
    float total = ws4[0] + ws4[1] + ws4[2] + ws4[3];
    float r = rsqrtf(total * (1.f / 4096.f) + 1e-6f);
    const int mt = row >> 4, l16 = row & 15;
#pragma unroll
    for (int c2 = 0; c2 < 2; ++c2) {
        int c = threadIdx.x * 2 + c2;        // 8-elem chunk index 0..511
        int kb = c >> 2, qq = c & 3;
        u16 o8[8];
#pragma unroll
        for (int j = 0; j < 8; ++j) {
            int i = c * 8 + j;
            o8[j] = f2h_(x[i] * r * w[i]);
        }
        *(uint4*)(out + ((size_t)(kb * 8 + mt) * 64 + qq * 16 + l16) * 8) = *(const uint4*)o8;
    }
}

// ---------------------------------------------------------------------------
// AWQ GEMM, barrier-free. A in Afrag layout. Per wave: 128m x 32n strip.
// BK=64 per iter. Private per-wave LDS B buffer (in-order LDS => no barrier).
// qw read: per-lane dwordx4 row load (lane l <- row k0+l, 4 strip dwords),
// routed to dequant lanes via ds_bpermute (no scattered global loads).
// Split-K partials (fp16, row-major [sk][128][N]).
// ---------------------------------------------------------------------------
__launch_bounds__(256, 2)
__global__ void gemm_awq(const u16* __restrict__ A, const int* __restrict__ qw,
                         const int* __restrict__ qz, const float* __restrict__ sc,
                         u16* __restrict__ part,
                         int qws, int scs, int N, int K, int kchunk) {
    // per-wave region: 32 rows x 144 B (64 fp16 + 16B pad). stride 36 words
    // == 4 mod 32 -> worst 2-way on b128 reads (free); b32 writes conflict-free.
    __shared__ __align__(16) char ldsB[4 * 4608];

    const int tid = threadIdx.x, w = tid >> 6, lane = tid & 63;
    const int q = lane >> 4, l16 = lane & 15;
    const int n0w = blockIdx.x * 128 + w * 32;
    const int pc0 = n0w >> 3;                 // strip's packed-col base
    const int kp = lane & 31, h = lane >> 5;
    const int sk = blockIdx.y, kc0 = sk * kchunk, kend = min(kc0 + kchunk, K);

    char* myB   = ldsB + w * 4608;
    char* wbase = myB + kp * 4;
    const u16* Ala = A + lane * 8;
    const int* qws_base = qw + pc0;           // lane row-load base (cols pc0..pc0+3)

    f32x4 acc[8][2] = {};
    h2 mzv[8], s2v[8];
    const int SH[8] = {0, 16, 4, 20, 8, 24, 12, 28};

    // one coalesced row-load: lane l gets row k0+l, 4 strip dwords (16 B)
    auto ldraw = [&](int k0) -> uint4 {
        return *(const uint4*)(qws_base + (size_t)(k0 + lane) * qws);
    };
    // crossbar-route a raw round to this lane's (kp,h) dequant quad
    auto route = [&](uint4 rv, u32* d) {
        const int i0 = kp * 8, i1 = i0 + 4;   // src lanes 2kp, 2kp+1 (byte idx)
        int b00 = __builtin_amdgcn_ds_bpermute(i0, (int)rv.x);
        int b10 = __builtin_amdgcn_ds_bpermute(i0, (int)rv.y);
        int b20 = __builtin_amdgcn_ds_bpermute(i0, (int)rv.z);
        int b30 = __builtin_amdgcn_ds_bpermute(i0, (int)rv.w);
        int b01 = __builtin_amdgcn_ds_bpermute(i1, (int)rv.x);
        int b11 = __builtin_amdgcn_ds_bpermute(i1, (int)rv.y);
        int b21 = __builtin_amdgcn_ds_bpermute(i1, (int)rv.z);
        int b31 = __builtin_amdgcn_ds_bpermute(i1, (int)rv.w);
        d[0] = (u32)(h ? b10 : b00);   // row 2kp,   col pc0+h
        d[1] = (u32)(h ? b11 : b01);   // row 2kp+1, col pc0+h
        d[2] = (u32)(h ? b30 : b20);   // row 2kp,   col pc0+h+2
        d[3] = (u32)(h ? b31 : b21);   // row 2kp+1, col pc0+h+2
    };
    auto conv = [&](u32 z, const float* s8) {
#pragma unroll
        for (int j = 0; j < 8; ++j) {
            u32 zj = (z >> SH[j]) & 15u;
            mzv[j] = __builtin_bit_cast(h2, 0xE400E400u | zj | (zj << 16));
            _Float16 hs = (_Float16)s8[j];
            s2v[j] = (h2){hs, hs};
        }
    };
    auto emit8 = [&](u32 w0, u32 w1, int nb) {
        char* bb = wbase + nb * 144;
        u32 w0s = w0 >> 4, w1s = w1 >> 4;
        auto em = [&](int j, u32 a0, u32 a1, int b) {
            u32 t = __builtin_amdgcn_perm(a1, a0, (u32)(b | ((b + 4) << 16)));
            u32 u = (t & 0x000F000Fu) | 0x64006400u;     // fp16 (1024+n) pair
            h2 v = (__builtin_bit_cast(h2, u) + mzv[j]) * s2v[j];
            *(u32*)(bb + j * 144) = __builtin_bit_cast(u32, v);
        };
        em(0, w0, w1, 0);  em(4, w0, w1, 1);  em(1, w0, w1, 2);  em(5, w0, w1, 3);
        em(2, w0s, w1s, 0); em(6, w0s, w1s, 1); em(3, w0s, w1s, 2); em(7, w0s, w1s, 3);
    };

    const int pA = pc0 + h, pB = pc0 + h + 2;    // for qz reads (small, coalesced)

    // ---- prologue: raw rounds 0,1; dequant step 0 ----
    uint4 rv_c = ldraw(kc0);
    uint4 rv_n = {0, 0, 0, 0};
    if (kc0 + 64 < kend) rv_n = ldraw(kc0 + 64);
    {
        int g = kc0 >> 7;
        u32 z0 = (u32)qz[(size_t)g * qws + pA], z1 = (u32)qz[(size_t)g * qws + pB];
        const float* sb = sc + (size_t)g * scs + n0w + h * 8;
        float s8a[8], s8b[8];
        *(float4*)&s8a[0] = *(const float4*)sb;        *(float4*)&s8a[4] = *(const float4*)(sb + 4);
        *(float4*)&s8b[0] = *(const float4*)(sb + 16); *(float4*)&s8b[4] = *(const float4*)(sb + 20);
        u32 qc[4];
        route(rv_c, qc);
        conv(z0, s8a); emit8(qc[0], qc[1], h * 8);
        conv(z1, s8b); emit8(qc[2], qc[3], 16 + h * 8);
    }

    // ---- barrier-free main loop ----
    for (int k0 = kc0; k0 < kend; k0 += 64) {
        const bool kn1 = (k0 + 64) < kend, kn2 = (k0 + 128) < kend;
        // z/sc loads for step s+1
        u32 z0 = 0, z1 = 0; float s8a[8], s8b[8];
        if (kn1) {
            int g = (k0 + 64) >> 7;
            z0 = (u32)qz[(size_t)g * qws + pA]; z1 = (u32)qz[(size_t)g * qws + pB];
            const float* sb = sc + (size_t)g * scs + n0w + h * 8;
            *(float4*)&s8a[0] = *(const float4*)sb;        *(float4*)&s8a[4] = *(const float4*)(sb + 4);
            *(float4*)&s8b[0] = *(const float4*)(sb + 16); *(float4*)&s8b[4] = *(const float4*)(sb + 20);
        }
        // A-frag loads (coalesced), consumed by MFMA at iter end
        uint4 af[2][8];
        const int kb0 = k0 >> 5;
#pragma unroll
        for (int c = 0; c < 2; ++c)
#pragma unroll
            for (int mt = 0; mt < 8; ++mt)
                af[c][mt] = *(const uint4*)(Ala + (size_t)((kb0 + c) * 8 + mt) * 512);
        // B-frag reads for step s (writes from prev iter long drained)
        uint4 bv[2][2];
#pragma unroll
        for (int c = 0; c < 2; ++c)
#pragma unroll
            for (int nt = 0; nt < 2; ++nt)
                bv[c][nt] = *(const uint4*)(myB + (nt * 16 + l16) * 144 + c * 64 + q * 16);
        // raw prefetch for step s+2 (depth-2)
        uint4 rv_f = {0, 0, 0, 0};
        if (kn2) rv_f = ldraw(k0 + 128);
        // dequant step s+1 into same private region (in-order LDS after reads)
        if (kn1) {
            u32 qn[4];
            route(rv_n, qn);
            conv(z0, s8a); emit8(qn[0], qn[1], h * 8);
            conv(z1, s8b); emit8(qn[2], qn[3], 16 + h * 8);
        }
        // MFMA step s
#pragma unroll
        for (int c = 0; c < 2; ++c)
#pragma unroll
            for (int mt = 0; mt < 8; ++mt)
#pragma unroll
                for (int nt = 0; nt < 2; ++nt)
                    acc[mt][nt] = __builtin_amdgcn_mfma_f32_16x16x32_f16(
                        __builtin_bit_cast(h8, af[c][mt]),
                        __builtin_bit_cast(h8, bv[c][nt]),
                        acc[mt][nt], 0, 0, 0);
        rv_n = rv_f;
    }

    // ---- epilogue: fp16 partial store (row-major plane) ----
    u16* pp = part + (size_t)sk * M_TOK * N;
#pragma unroll
    for (int mt = 0; mt < 8; ++mt)
#pragma unroll
        for (int nt = 0; nt < 2; ++nt) {
            const int n = n0w + nt * 16 + l16;
#pragma unroll
            for (int r = 0; r < 4; ++r) {
                const int m = mt * 16 + q * 4 + r;
                pp[(size_t)m * N + n] = f2h_(acc[mt][nt][r]);
            }
        }
}

// ---------------------------------------------------------------------------
// Reduce SK fp16 partial planes [sk][128][4096] -> fp16 in Afrag layout
// ---------------------------------------------------------------------------
__launch_bounds__(256)
__global__ void reduce_to_afrag(const u16* __restrict__ part, u16* __restrict__ out,
                                int SK) {
    const int idx = blockIdx.x * 256 + threadIdx.x;   // 0..65535
    const int m = idx >> 9, c = idx & 511;
    float s[8] = {};
    for (int k = 0; k < SK; ++k)
        acc8(*(const uint4*)(part + (size_t)k * 524288 + (size_t)m * 4096 + c * 8), s);
    const int kb = c >> 2, qq = c & 3, mt = m >> 4, l16 = m & 15;
    u16 o8[8];
#pragma unroll
    for (int j = 0; j < 8; ++j) o8[j] = f2h_(s[j]);
    *(uint4*)(out + ((size_t)(kb * 8 + mt) * 64 + qq * 16 + l16) * 8) = *(const uint4*)o8;
}

// Reduce SK fp16 partial planes + fp32 residual -> fp32 (row-major)
__launch_bounds__(256)
__global__ void reduce_add_f32(const u16* __restrict__ part, const float* __restrict__ resin,
                               float* __restrict__ out, int SK) {
    const int idx = blockIdx.x * 256 + threadIdx.x;
    const size_t base = (size_t)idx * 8;
    float s[8];
    *(float4*)&s[0] = *(const float4*)(resin + base);
    *(float4*)&s[4] = *(const float4*)(resin + base + 4);
    for (int k = 0; k < SK; ++k)
        acc8(*(const uint4*)(part + (size_t)k * 524288 + base), s);
    *(float4*)(out + base)     = *(const float4*)&s[0];
    *(float4*)(out + base + 4) = *(const float4*)&s[4];
}

// ---------------------------------------------------------------------------
// SiLU(gate)*up from gu partials [3][128][22016] -> act fp16 in Afrag layout
// ---------------------------------------------------------------------------
__launch_bounds__(256)
__global__ void silu_mul(const u16* __restrict__ part, u16* __restrict__ act) {
    const int idx = blockIdx.x * 256 + threadIdx.x;   // 0..176127
    const int m = idx / 1376, c = idx - m * 1376;
    const int nb = c * 8;
    float g[8] = {}, u[8] = {};
    for (int k = 0; k < 3; ++k) {
        const size_t base = (size_t)k * 2818048 + (size_t)m * 22016 + nb;
        acc8(*(const uint4*)(part + base), g);
        acc8(*(const uint4*)(part + base + 11008), u);
    }
    const int kb = nb >> 5, qq = (nb >> 3) & 3, mt = m >> 4, l16 = m & 15;
    u16 o8[8];
#pragma unroll
    for (int j = 0; j < 8; ++j) {
        float a = g[j] / (1.f + __expf(-g[j])) * u[j];
        o8[j] = f2h_(a);
    }
    *(uint4*)(act + ((size_t)(kb * 8 + mt) * 64 + qq * 16 + l16) * 8) = *(const uint4*)o8;
}

// ---------------------------------------------------------------------------
extern "C" void kernel_launch(void* const* d_in, const int* in_sizes, int n_in,
                              void* d_out, int out_size, void* d_ws, size_t ws_size,
                              hipStream_t stream) {
    const float* x      = (const float*)d_in[0];
    const float* ln1_w  = (const float*)d_in[1];
    const float* ln2_w  = (const float*)d_in[2];
    const int*   qkv_qw = (const int*)d_in[3];
    const int*   qkv_qz = (const int*)d_in[4];
    const float* qkv_sc = (const float*)d_in[5];
    const int*   o_qw   = (const int*)d_in[6];
    const int*   o_qz   = (const int*)d_in[7];
    const float* o_sc   = (const float*)d_in[8];
    const int*   gu_qw  = (const int*)d_in[9];
    const int*   gu_qz  = (const int*)d_in[10];
    const float* gu_sc  = (const float*)d_in[11];
    const int*   dn_qw  = (const int*)d_in[12];
    const int*   dn_qz  = (const int*)d_in[13];
    const float* dn_sc  = (const float*)d_in[14];
    float* out = (float*)d_out;

    // ws layout (~22.9 MB, same as R4)
    char* ws = (char*)d_ws;
    u16*   pbuf = (u16*)(ws);                 // partials: max 16.9 MB (gu SK=3)
    u16*   act  = (u16*)(ws + 16908288);      // 2.75 MB fp16 (Afrag)
    float* res2 = (float*)(ws + 19726336);    // 2 MB fp32
    u16*   slot = (u16*)(ws + 21823488);      // 1 MB fp16 Afrag (h1/qb/h2)

    // h1 = rmsnorm(x, ln1)  -> Afrag
    rmsnorm_k<<<128, 256, 0, stream>>>(x, ln1_w, slot);

    // q = h1 @ Wqkv[:, :4096]   (32 tiles x SK16, kchunk=256)
    gemm_awq<<<dim3(32, 16), 256, 0, stream>>>(slot, qkv_qw, qkv_qz, qkv_sc, pbuf,
                                               1536, 12288, 4096, 4096, 256);
    reduce_to_afrag<<<256, 256, 0, stream>>>(pbuf, slot, 16);

    // attn = q @ Wo ; res2 = x + attn
    gemm_awq<<<dim3(32, 16), 256, 0, stream>>>(slot, o_qw, o_qz, o_sc, pbuf,
                                               512, 4096, 4096, 4096, 256);
    reduce_add_f32<<<256, 256, 0, stream>>>(pbuf, x, res2, 16);

    // h2 = rmsnorm(res2, ln2) -> Afrag
    rmsnorm_k<<<128, 256, 0, stream>>>(res2, ln2_w, slot);

    // gate_up = h2 @ Wgu   (172 tiles x SK3, kchunk=1408)
    gemm_awq<<<dim3(172, 3), 256, 0, stream>>>(slot, gu_qw, gu_qz, gu_sc, pbuf,
                                               2752, 22016, 22016, 4096, 1408);
    silu_mul<<<688, 256, 0, stream>>>(pbuf, act);

    // down = act @ Wdn   (32 tiles x SK16, kchunk=704); out = res2 + down
    gemm_awq<<<dim3(32, 16), 256, 0, stream>>>(act, dn_qw, dn_qz, dn_sc, pbuf,
                                               512, 4096, 4096, 11008, 704);
    reduce_add_f32<<<256, 256, 0, stream>>>(pbuf, res2, out, 16);
}

// Round 6
// 303.967 us; speedup vs baseline: 1.3396x; 1.0459x over previous
//
#include <hip/hip_runtime.h>

typedef unsigned int   u32;
typedef unsigned short u16;

typedef _Float16 h2  __attribute__((ext_vector_type(2)));
typedef _Float16 h8  __attribute__((ext_vector_type(8)));
typedef float    f32x4 __attribute__((ext_vector_type(4)));

#define M_TOK 128

__device__ __forceinline__ u16 f2h_(float f) {
    _Float16 h = (_Float16)f; return __builtin_bit_cast(u16, h);
}
__device__ __forceinline__ float h2f_(u16 b) {
    _Float16 h = __builtin_bit_cast(_Float16, b); return (float)h;
}
__device__ __forceinline__ void acc8(uint4 v, float* s) {
#pragma unroll
    for (int i = 0; i < 4; ++i) {
        u32 w = ((const u32*)&v)[i];
        s[2 * i]     += h2f_((u16)(w & 0xFFFF));
        s[2 * i + 1] += h2f_((u16)(w >> 16));
    }
}

// AWQ nibble order: n&7 = j sits at bit position SH[j]
__constant__ int SHC[8] = {0, 16, 4, 20, 8, 24, 12, 28};

// ---------------------------------------------------------------------------
// pack_zs: (qz, sc) -> zs[g][n] u32 { lo16: fp16(-(1024+z)), hi16: fp16(sc) }
// ---------------------------------------------------------------------------
__launch_bounds__(256)
__global__ void pack_zs(const int* __restrict__ qz, const float* __restrict__ sc,
                        u32* __restrict__ zs, int qws, int scs, int Ncols, int total) {
    const int idx = blockIdx.x * 256 + threadIdx.x;
    if (idx >= total) return;
    const int g = idx / Ncols, n = idx - g * Ncols;
    const u32 d = (u32)qz[(size_t)g * qws + (n >> 3)];
    const u32 zj = (d >> SHC[n & 7]) & 15u;
    const u32 mz = 0xE400u | zj;                    // fp16 -(1024+z)
    const u16 sh = f2h_(sc[(size_t)g * scs + n]);
    zs[(size_t)g * Ncols + n] = mz | ((u32)sh << 16);
}

// A-fragment-major layout: elem offset for logical (m, k):
//   kb=k/32, q=(k/8)&3, j=k&7, mt=m/16, l16=m&15
//   off = ((kb*8+mt)*64 + q*16 + l16)*8 + j    (fp16 elements)

// ---------------------------------------------------------------------------
// RMSNorm: one block per token row, fp32 in -> fp16 out in Afrag layout
// ---------------------------------------------------------------------------
__launch_bounds__(256)
__global__ void rmsnorm_k(const float* __restrict__ in, const float* __restrict__ w,
                          u16* __restrict__ out) {
    const int row = blockIdx.x;
    const float* x = in + (size_t)row * 4096;
    float ss = 0.f;
#pragma unroll
    for (int j = 0; j < 16; ++j) {
        float v = x[threadIdx.x + 256 * j];
        ss += v * v;
    }
#pragma unroll
    for (int off = 32; off > 0; off >>= 1) ss += __shfl_down(ss, off, 64);
    __shared__ float ws4[4];
    if ((threadIdx.x & 63) == 0) ws4[threadIdx.x >> 6] = ss;
    __syncthreads();
    float total = ws4[0] + ws4[1] + ws4[2] + ws4[3];
    float r = rsqrtf(total * (1.f / 4096.f) + 1e-6f);
    const int mt = row >> 4, l16 = row & 15;
#pragma unroll
    for (int c2 = 0; c2 < 2; ++c2) {
        int c = threadIdx.x * 2 + c2;
        int kb = c >> 2, qq = c & 3;
        u16 o8[8];
#pragma unroll
        for (int j = 0; j < 8; ++j) {
            int i = c * 8 + j;
            o8[j] = f2h_(x[i] * r * w[i]);
        }
        *(uint4*)(out + ((size_t)(kb * 8 + mt) * 64 + qq * 16 + l16) * 8) = *(const uint4*)o8;
    }
}

// ---------------------------------------------------------------------------
// AWQ GEMM, barrier-free, A depth-2 register double-buffer.
// Per wave: 128m x 32n strip, BK=64/iter, private LDS B (in-order, no barrier).
// qw: per-lane row dwordx4 + ds_bpermute route. zs: prepacked fp16 pairs.
// ---------------------------------------------------------------------------
__launch_bounds__(256, 2)
__global__ void gemm_awq(const u16* __restrict__ A, const u32* __restrict__ zs,
                         const int* __restrict__ qw, u16* __restrict__ part,
                         int qws, int N, int K, int kchunk) {
    __shared__ __align__(16) char ldsB[4 * 4608];   // per-wave 32 rows x 144 B

    const int tid = threadIdx.x, w = tid >> 6, lane = tid & 63;
    const int q = lane >> 4, l16 = lane & 15;
    const int n0w = blockIdx.x * 128 + w * 32;
    const int pc0 = n0w >> 3;
    const int kp = lane & 31, h = lane >> 5;
    const int sk = blockIdx.y, kc0 = sk * kchunk, kend = min(kc0 + kchunk, K);

    char* myB   = ldsB + w * 4608;
    char* wbase = myB + kp * 4;
    const u16* Ala = A + lane * 8;
    const int* qws_base = qw + pc0;
    const u32* zsA = zs + n0w + h * 8;
    const u32* zsB = zs + n0w + 16 + h * 8;

    f32x4 acc[8][2] = {};
    uint4 za0, za1, zb0, zb1;       // current group's packed (mz, sc)

    auto ldraw = [&](int k0) -> uint4 {
        return *(const uint4*)(qws_base + (size_t)(k0 + lane) * qws);
    };
    auto loadzs = [&](int g) {
        za0 = *(const uint4*)(zsA + (size_t)g * N);
        za1 = *(const uint4*)(zsA + (size_t)g * N + 4);
        zb0 = *(const uint4*)(zsB + (size_t)g * N);
        zb1 = *(const uint4*)(zsB + (size_t)g * N + 4);
    };
    auto route = [&](uint4 rv, u32* d) {
        const int i0 = kp * 8, i1 = i0 + 4;
        int b00 = __builtin_amdgcn_ds_bpermute(i0, (int)rv.x);
        int b10 = __builtin_amdgcn_ds_bpermute(i0, (int)rv.y);
        int b20 = __builtin_amdgcn_ds_bpermute(i0, (int)rv.z);
        int b30 = __builtin_amdgcn_ds_bpermute(i0, (int)rv.w);
        int b01 = __builtin_amdgcn_ds_bpermute(i1, (int)rv.x);
        int b11 = __builtin_amdgcn_ds_bpermute(i1, (int)rv.y);
        int b21 = __builtin_amdgcn_ds_bpermute(i1, (int)rv.z);
        int b31 = __builtin_amdgcn_ds_bpermute(i1, (int)rv.w);
        d[0] = (u32)(h ? b10 : b00);
        d[1] = (u32)(h ? b11 : b01);
        d[2] = (u32)(h ? b30 : b20);
        d[3] = (u32)(h ? b31 : b21);
    };
    // dequant one octet (8 n) of a 64k strip-tile; zs unpacked per-element
    auto emit8 = [&](u32 w0, u32 w1, int nb, uint4 z0, uint4 z1) {
        char* bb = wbase + nb * 144;
        u32 w0s = w0 >> 4, w1s = w1 >> 4;
        auto em = [&](int j, u32 a0, u32 a1, int b, u32 zsj) {
            h2 mz = __builtin_bit_cast(h2, __builtin_amdgcn_perm(zsj, zsj, 0x01000100u));
            h2 s2 = __builtin_bit_cast(h2, __builtin_amdgcn_perm(zsj, zsj, 0x03020302u));
            u32 t = __builtin_amdgcn_perm(a1, a0, (u32)(b | ((b + 4) << 16)));
            u32 u = (t & 0x000F000Fu) | 0x64006400u;
            h2 v = (__builtin_bit_cast(h2, u) + mz) * s2;
            *(u32*)(bb + j * 144) = __builtin_bit_cast(u32, v);
        };
        em(0, w0, w1, 0, z0.x);  em(4, w0, w1, 1, z1.x);
        em(1, w0, w1, 2, z0.y);  em(5, w0, w1, 3, z1.y);
        em(2, w0s, w1s, 0, z0.z); em(6, w0s, w1s, 1, z1.z);
        em(3, w0s, w1s, 2, z0.w); em(7, w0s, w1s, 3, z1.w);
    };
    auto lda = [&](int k, uint4(&dst)[2][8]) {
        const int kb = k >> 5;
#pragma unroll
        for (int c = 0; c < 2; ++c)
#pragma unroll
            for (int mt = 0; mt < 8; ++mt)
                dst[c][mt] = *(const uint4*)(Ala + (size_t)((kb + c) * 8 + mt) * 512);
    };

    uint4 afA[2][8], afB[2][8];
    uint4 rv_n = {0,0,0,0};

    // ---- prologue ----
    loadzs(kc0 >> 7);
    uint4 rv0 = ldraw(kc0);
    if (kc0 + 64 < kend) rv_n = ldraw(kc0 + 64);
    lda(kc0, afA);
    {
        u32 qd[4];
        route(rv0, qd);
        emit8(qd[0], qd[1], h * 8, za0, za1);
        emit8(qd[2], qd[3], 16 + h * 8, zb0, zb1);
    }
    if (((kc0 + 64) & 127) == 0 && kc0 + 64 < kend)
        loadzs((kc0 + 64) >> 7);        // dn odd-sk mid-group start

    // ---- main loop: unrolled ping-pong pair ----
    auto step = [&](int k0, uint4(&cur)[2][8], uint4(&nxt)[2][8]) {
        const bool kn1 = (k0 + 64) < kend, kn2 = (k0 + 128) < kend;
        if (kn1) lda(k0 + 64, nxt);                   // A(i+1), consumed next step
        // B-frags(i): region written during previous step (same-wave order)
        uint4 bv[2][2];
#pragma unroll
        for (int c = 0; c < 2; ++c)
#pragma unroll
            for (int nt = 0; nt < 2; ++nt)
                bv[c][nt] = *(const uint4*)(myB + (nt * 16 + l16) * 144 + c * 64 + q * 16);
        uint4 rv_f = {0,0,0,0};
        if (kn2) rv_f = ldraw(k0 + 128);              // raw(i+2)
        if (kn1) {                                    // dequant(i+1)
            u32 qd[4];
            route(rv_n, qd);
            emit8(qd[0], qd[1], h * 8, za0, za1);
            emit8(qd[2], qd[3], 16 + h * 8, zb0, zb1);
        }
        if (kn2 && (((k0 + 128) & 127) == 0))         // zs(group+1), used next step
            loadzs((k0 + 128) >> 7);
        // MFMA(i): all operands from previous step
#pragma unroll
        for (int c = 0; c < 2; ++c)
#pragma unroll
            for (int mt = 0; mt < 8; ++mt)
#pragma unroll
                for (int nt = 0; nt < 2; ++nt)
                    acc[mt][nt] = __builtin_amdgcn_mfma_f32_16x16x32_f16(
                        __builtin_bit_cast(h8, cur[c][mt]),
                        __builtin_bit_cast(h8, bv[c][nt]),
                        acc[mt][nt], 0, 0, 0);
        rv_n = rv_f;
    };
    for (int k0 = kc0; k0 < kend; k0 += 128) {
        step(k0, afA, afB);
        if (k0 + 64 < kend) step(k0 + 64, afB, afA);
    }

    // ---- epilogue: fp16 partial store ----
    u16* pp = part + (size_t)sk * M_TOK * N;
#pragma unroll
    for (int mt = 0; mt < 8; ++mt)
#pragma unroll
        for (int nt = 0; nt < 2; ++nt) {
            const int n = n0w + nt * 16 + l16;
#pragma unroll
            for (int r = 0; r < 4; ++r) {
                const int m = mt * 16 + q * 4 + r;
                pp[(size_t)m * N + n] = f2h_(acc[mt][nt][r]);
            }
        }
}

// ---------------------------------------------------------------------------
__launch_bounds__(256)
__global__ void reduce_to_afrag(const u16* __restrict__ part, u16* __restrict__ out,
                                int SK) {
    const int idx = blockIdx.x * 256 + threadIdx.x;
    const int m = idx >> 9, c = idx & 511;
    float s[8] = {};
    for (int k = 0; k < SK; ++k)
        acc8(*(const uint4*)(part + (size_t)k * 524288 + (size_t)m * 4096 + c * 8), s);
    const int kb = c >> 2, qq = c & 3, mt = m >> 4, l16 = m & 15;
    u16 o8[8];
#pragma unroll
    for (int j = 0; j < 8; ++j) o8[j] = f2h_(s[j]);
    *(uint4*)(out + ((size_t)(kb * 8 + mt) * 64 + qq * 16 + l16) * 8) = *(const uint4*)o8;
}

__launch_bounds__(256)
__global__ void reduce_add_f32(const u16* __restrict__ part, const float* __restrict__ resin,
                               float* __restrict__ out, int SK) {
    const int idx = blockIdx.x * 256 + threadIdx.x;
    const size_t base = (size_t)idx * 8;
    float s[8];
    *(float4*)&s[0] = *(const float4*)(resin + base);
    *(float4*)&s[4] = *(const float4*)(resin + base + 4);
    for (int k = 0; k < SK; ++k)
        acc8(*(const uint4*)(part + (size_t)k * 524288 + base), s);
    *(float4*)(out + base)     = *(const float4*)&s[0];
    *(float4*)(out + base + 4) = *(const float4*)&s[4];
}

__launch_bounds__(256)
__global__ void silu_mul(const u16* __restrict__ part, u16* __restrict__ act) {
    const int idx = blockIdx.x * 256 + threadIdx.x;
    const int m = idx / 1376, c = idx - m * 1376;
    const int nb = c * 8;
    float g[8] = {}, u[8] = {};
    for (int k = 0; k < 3; ++k) {
        const size_t base = (size_t)k * 2818048 + (size_t)m * 22016 + nb;
        acc8(*(const uint4*)(part + base), g);
        acc8(*(const uint4*)(part + base + 11008), u);
    }
    const int kb = nb >> 5, qq = (nb >> 3) & 3, mt = m >> 4, l16 = m & 15;
    u16 o8[8];
#pragma unroll
    for (int j = 0; j < 8; ++j) {
        float a = g[j] / (1.f + __expf(-g[j])) * u[j];
        o8[j] = f2h_(a);
    }
    *(uint4*)(act + ((size_t)(kb * 8 + mt) * 64 + qq * 16 + l16) * 8) = *(const uint4*)o8;
}

// ---------------------------------------------------------------------------
extern "C" void kernel_launch(void* const* d_in, const int* in_sizes, int n_in,
                              void* d_out, int out_size, void* d_ws, size_t ws_size,
                              hipStream_t stream) {
    const float* x      = (const float*)d_in[0];
    const float* ln1_w  = (const float*)d_in[1];
    const float* ln2_w  = (const float*)d_in[2];
    const int*   qkv_qw = (const int*)d_in[3];
    const int*   qkv_qz = (const int*)d_in[4];
    const float* qkv_sc = (const float*)d_in[5];
    const int*   o_qw   = (const int*)d_in[6];
    const int*   o_qz   = (const int*)d_in[7];
    const float* o_sc   = (const float*)d_in[8];
    const int*   gu_qw  = (const int*)d_in[9];
    const int*   gu_qz  = (const int*)d_in[10];
    const float* gu_sc  = (const float*)d_in[11];
    const int*   dn_qw  = (const int*)d_in[12];
    const int*   dn_qz  = (const int*)d_in[13];
    const float* dn_sc  = (const float*)d_in[14];
    float* out = (float*)d_out;

    // ws layout (~25.7 MB)
    char* ws = (char*)d_ws;
    u16*   pbuf = (u16*)(ws);                 // partials: max 16.9 MB (gu SK3)
    u32*   zsb  = (u32*)(ws + 16908288);      // 2.82 MB, reused per gemm
    u16*   act  = (u16*)(ws + 19726336);      // 2.75 MB fp16 (Afrag)
    float* res2 = (float*)(ws + 22544384);    // 2 MB fp32
    u16*   slot = (u16*)(ws + 24641536);      // 1 MB fp16 Afrag (h1/qb/h2)

    // h1 = rmsnorm(x, ln1) -> Afrag ; zs for qkv
    rmsnorm_k<<<128, 256, 0, stream>>>(x, ln1_w, slot);
    pack_zs<<<512, 256, 0, stream>>>(qkv_qz, qkv_sc, zsb, 1536, 12288, 4096, 131072);

    // q = h1 @ Wqkv[:, :4096]   (32 tiles x SK16, kchunk 256)
    gemm_awq<<<dim3(32, 16), 256, 0, stream>>>(slot, zsb, qkv_qw, pbuf,
                                               1536, 4096, 4096, 256);
    reduce_to_afrag<<<256, 256, 0, stream>>>(pbuf, slot, 16);
    pack_zs<<<512, 256, 0, stream>>>(o_qz, o_sc, zsb, 512, 4096, 4096, 131072);

    // attn = q @ Wo ; res2 = x + attn
    gemm_awq<<<dim3(32, 16), 256, 0, stream>>>(slot, zsb, o_qw, pbuf,
                                               512, 4096, 4096, 256);
    reduce_add_f32<<<256, 256, 0, stream>>>(pbuf, x, res2, 16);

    // h2 = rmsnorm(res2, ln2) -> Afrag ; zs for gu
    rmsnorm_k<<<128, 256, 0, stream>>>(res2, ln2_w, slot);
    pack_zs<<<2752, 256, 0, stream>>>(gu_qz, gu_sc, zsb, 2752, 22016, 22016, 704512);

    // gate_up = h2 @ Wgu   (172 tiles x SK3, kchunk 1408)
    gemm_awq<<<dim3(172, 3), 256, 0, stream>>>(slot, zsb, gu_qw, pbuf,
                                               2752, 22016, 4096, 1408);
    silu_mul<<<688, 256, 0, stream>>>(pbuf, act);
    pack_zs<<<1376, 256, 0, stream>>>(dn_qz, dn_sc, zsb, 512, 4096, 4096, 352256);

    // down = act @ Wdn   (32 tiles x SK16, kchunk 704); out = res2 + down
    gemm_awq<<<dim3(32, 16), 256, 0, stream>>>(act, zsb, dn_qw, pbuf,
                                               512, 4096, 11008, 704);
    reduce_add_f32<<<256, 256, 0, stream>>>(pbuf, res2, out, 16);
}